// Round 9
// baseline (226.080 us; speedup 1.0000x reference)
//
#include <hip/hip_runtime.h>
#include <math.h>

#define CUTOFF    0.3927f
#define TWO_PI_F  6.283185307179586f
#define INV_2PI_F 0.15915494309189535f
#define INV_SQRT2 0.7071067811865476f
#define NB        4
#define NNODE     2048
#define HD        128
#define S_TAB     256
#define SG        8

__device__ __forceinline__ float sigmoidf_(float x){ return 1.0f/(1.0f+__expf(-x)); }
__device__ __forceinline__ float siluf_(float x){ return x*sigmoidf_(x); }
__device__ __forceinline__ float ssiluf_(float x){ return siluf_(x)*(1.0f/0.6f); }

// ---------------- table build: one block = (l, b, 8 samples) ----------------
struct TabSmem { float X[SG][HD+4]; float g[16]; int probe; };

__device__ __forceinline__ float4 gemv4(const float (*X)[HD+4], int sl,
                                        const float* __restrict__ W, int j0){
    float a0=0.f, a1=0.f, a2=0.f, a3=0.f;
    #pragma unroll 8
    for (int k=0;k<HD;k++){
        float x = X[sl][k];
        float4 w = *(const float4*)(W + k*HD + j0);
        a0 += x*w.x; a1 += x*w.y; a2 += x*w.z; a3 += x*w.w;
    }
    return make_float4(a0,a1,a2,a3);
}

__device__ void table_block(int blk, int tid,
                            const int* __restrict__ src, const float* __restrict__ globs_e,
                            int ne,
                            const float* __restrict__ W_e0, const float* __restrict__ W_r1,
                            const float* __restrict__ W_r2, const float* __restrict__ W_g,
                            const float* __restrict__ W_v1, const float* __restrict__ W_v2,
                            const float* __restrict__ W_vo, float* __restrict__ table,
                            TabSmem& sm){
    int sl = tid >> 5, jq = tid & 31, j0 = jq*4;
    int sg = blk & 31, b = (blk>>5)&3, l = blk>>7;

    // probe an edge of batch b to recover globs[b]
    if (tid == 0) sm.probe = 0x7fffffff;
    __syncthreads();
    int stride = ne >> 8; if (stride < 1) stride = 1;
    int e = tid*stride; if (e >= ne) e = ne-1;
    if ((src[e] >> 11) == b) atomicMin(&sm.probe, e);
    __syncthreads();
    int pe = sm.probe; if (pe == 0x7fffffff) pe = 0;
    if (tid < 16) sm.g[tid] = globs_e[(size_t)pe*16 + tid];
    __syncthreads();

    const float step = CUTOFF / (S_TAB - 1);
    float rd = (sg*SG + sl)*step;

    const float* We0 = W_e0 + l*17*HD;
    const float* Wr1 = W_r1 + l*HD*HD;
    const float* Wr2 = W_r2 + l*HD*HD;
    const float* Wg  = W_g  + l*HD;
    const float* Wv1 = W_v1 + l*HD*HD;
    const float* Wv2 = W_v2 + l*HD*HD;
    const float* Wvo = W_vo + l*HD;

    float4 p = make_float4(0,0,0,0);
    #pragma unroll
    for (int k=0;k<16;k++){
        float g = sm.g[k];
        float4 w = *(const float4*)(We0 + k*HD + j0);
        p.x += g*w.x; p.y += g*w.y; p.z += g*w.z; p.w += g*w.w;
    }
    float4 w16 = *(const float4*)(We0 + 16*HD + j0);
    float4 h;
    h.x = siluf_(ssiluf_(p.x + rd*w16.x));
    h.y = siluf_(ssiluf_(p.y + rd*w16.y));
    h.z = siluf_(ssiluf_(p.z + rd*w16.z));
    h.w = siluf_(ssiluf_(p.w + rd*w16.w));

    #define STORE4(v) { sm.X[sl][j0]=(v).x; sm.X[sl][j0+1]=(v).y; sm.X[sl][j0+2]=(v).z; sm.X[sl][j0+3]=(v).w; }
    #define SSILU4(v) make_float4(ssiluf_((v).x), ssiluf_((v).y), ssiluf_((v).z), ssiluf_((v).w))

    STORE4(h); __syncthreads();
    float4 t = gemv4(sm.X, sl, Wr1, j0); __syncthreads();
    t = SSILU4(t);
    STORE4(t); __syncthreads();
    float4 u = gemv4(sm.X, sl, Wr2, j0); __syncthreads();
    h.x = (h.x + ssiluf_(u.x))*INV_SQRT2;
    h.y = (h.y + ssiluf_(u.y))*INV_SQRT2;
    h.z = (h.z + ssiluf_(u.z))*INV_SQRT2;
    h.w = (h.w + ssiluf_(u.w))*INV_SQRT2;

    float4 wg = *(const float4*)(Wg + j0);
    float pg = h.x*wg.x + h.y*wg.y + h.z*wg.z + h.w*wg.w;
    #pragma unroll
    for (int off=16; off>0; off>>=1) pg += __shfl_xor(pg, off);
    float gt = sigmoidf_(pg);
    h.x*=gt; h.y*=gt; h.z*=gt; h.w*=gt;

    STORE4(h); __syncthreads();
    t = gemv4(sm.X, sl, Wv1, j0); __syncthreads();
    t = SSILU4(t);
    STORE4(t); __syncthreads();
    u = gemv4(sm.X, sl, Wv2, j0);
    float4 v;
    v.x = siluf_((h.x + ssiluf_(u.x))*INV_SQRT2);
    v.y = siluf_((h.y + ssiluf_(u.y))*INV_SQRT2);
    v.z = siluf_((h.z + ssiluf_(u.z))*INV_SQRT2);
    v.w = siluf_((h.w + ssiluf_(u.w))*INV_SQRT2);
    float4 wvo = *(const float4*)(Wvo + j0);
    float pv = v.x*wvo.x + v.y*wvo.y + v.z*wvo.z + v.w*wvo.w;
    #pragma unroll
    for (int off=16; off>0; off>>=1) pv += __shfl_xor(pv, off);
    if (jq == 0) table[(l*NB+b)*S_TAB + sg*SG + sl] = pv;
    #undef STORE4
    #undef SSILU4
}

__global__ __launch_bounds__(256)
void k_table_sa(const int* __restrict__ src, const float* __restrict__ globs_e,
                int ne,
                const float* __restrict__ W_e0, const float* __restrict__ W_r1,
                const float* __restrict__ W_r2, const float* __restrict__ W_g,
                const float* __restrict__ W_v1, const float* __restrict__ W_v2,
                const float* __restrict__ W_vo, float* __restrict__ table){
    __shared__ TabSmem tsm;
    table_block(blockIdx.x, threadIdx.x, src, globs_e, ne, W_e0, W_r1, W_r2,
                W_g, W_v1, W_v2, W_vo, table, tsm);
}

// ---------------- per-edge message ------------------------------------------
__device__ __forceinline__ bool edge_msg(const float* __restrict__ tab_b,
                                         float rx, float ry, float rd, float sc,
                                         float& mx, float& my){
    float d = rd * (1.0f/CUTOFF);
    if (d >= 1.0f) return false;
    float d2 = d*d;
    float d5 = d2*d2*d;
    float env = 1.0f + d5*(-21.0f + d*(35.0f + d*(-15.0f)));
    float u = rd * ((float)(S_TAB-1)/CUTOFF);
    int i1 = (int)u; if (i1 > S_TAB-1) i1 = S_TAB-1;
    float fr = u - (float)i1;
    int im = i1-1 < 0 ? 0 : i1-1;
    int i2 = i1+1 > S_TAB-1 ? S_TAB-1 : i1+1;
    int i3 = i1+2 > S_TAB-1 ? S_TAB-1 : i1+2;
    float p0=tab_b[im], p1=tab_b[i1], p2=tab_b[i2], p3=tab_b[i3];
    float mij = p1 + 0.5f*fr*((p2-p0) + fr*((2.f*p0-5.f*p1+4.f*p2-p3)
                               + fr*(3.f*(p1-p2)+p3-p0)));
    float nrm = sqrtf(rx*rx + ry*ry);
    float inv = 1.0f / fmaxf(nrm, 1e-8f);
    float wmul = mij * env * sc * inv;
    mx = wmul*rx; my = wmul*ry;
    return true;
}

// ---------------- N-body per-node aggregation -------------------------------
// Block = (batch, 16 target nodes). 256 threads = 16 t-lanes x 16 s-chunks
// of 128 sources. out[t] = cur[t] + sum_{kept pair (s,t)} msg(s->t).
// Membership is a bit-exact f32 replica of setup (wrap via rint; mul-vs-div
// rounding of x/2pi can only flip k near |x/2pi|~0.5 where d2 ~ pi^2 >> CUTOFF).
template<int LAYER>
__global__ __launch_bounds__(256, 2)
void k_nbody(const float* __restrict__ coors0, const float* __restrict__ ccur,
             const float* __restrict__ table_g, const float* __restrict__ scale,
             const int* __restrict__ src, const int* __restrict__ tgt,
             int ne, float* __restrict__ outp){
    __shared__ float2 c0s[NNODE];
    __shared__ float2 c1s[LAYER ? NNODE : 1];
    __shared__ float  tabs[S_TAB];
    __shared__ float2 sred[4][16];
    int tid = threadIdx.x, blk = blockIdx.x;
    int b  = blk >> 7;                 // 4 batches x 128 blocks
    int t0 = (blk & 127) * 16;
    int tl = tid & 15, sk = tid >> 4;  // 16 s-chunks x 128 sources

    const float2* cb0 = ((const float2*)coors0) + (b << 11);
    const float2* cb1 = ((const float2*)ccur)  + (b << 11);
    for (int i = tid; i < NNODE; i += 256) c0s[i] = cb0[i];
    if (LAYER == 1) for (int i = tid; i < NNODE; i += 256) c1s[i] = cb1[i];
    for (int i = tid; i < S_TAB; i += 256)
        tabs[i] = table_g[LAYER*NB*S_TAB + b*S_TAB + i];

    int ic  = src[ne-1];               // truncation frontier (global indices)
    int jcg = tgt[ne-1];
    bool keep_all = (ic == 0 && jcg == 0);   // padded => nothing dropped
    float sc = scale[LAYER];

    int t  = t0 + tl;
    int tg = (b << 11) + t;
    float2 ci0 = cb0[t];
    __syncthreads();
    float2 ci1 = (LAYER == 1) ? c1s[t] : ci0;

    float ax = 0.f, ay = 0.f;
    int base = sk * 128;
    int rot  = (sk & 3) * 2;           // bank-conflict-free rotation per chunk
    for (int ii = 0; ii < 128; ii++){
        int s = base + ((ii + rot) & 127);
        float2 cj = c0s[s];
        // membership: bit-exact setup replica (rel = c[t]-c[s], f32, no fma)
        float dx = __fsub_rn(ci0.x, cj.x);
        float dy = __fsub_rn(ci0.y, cj.y);
        float kx = rintf(dx * INV_2PI_F);
        float ky = rintf(dy * INV_2PI_F);
        float wx = __fsub_rn(dx, __fmul_rn(TWO_PI_F, kx));
        float wy = __fsub_rn(dy, __fmul_rn(TWO_PI_F, ky));
        float d2 = __fadd_rn(__fmul_rn(wx,wx), __fmul_rn(wy,wy));
        bool valid = (d2 > 0.0f) && (d2 <= CUTOFF);
        if (valid && !keep_all){
            int sg_ = (b << 11) + s;   // kept iff row-major rank <= frontier
            valid = (sg_ < ic) || (sg_ == ic && tg <= jcg);
        }
        if (valid){
            float rx, ry, rd;
            if (LAYER == 0){ rx = wx; ry = wy; rd = d2; }
            else {
                float2 cjs = c1s[s];
                rx = ci1.x - cjs.x; ry = ci1.y - cjs.y;
                rx -= TWO_PI_F * rintf(rx * INV_2PI_F);
                ry -= TWO_PI_F * rintf(ry * INV_2PI_F);
                rd = rx*rx + ry*ry;
            }
            float mx, my;
            if (edge_msg(tabs, rx, ry, rd, sc, mx, my)){
                ax += mx; ay += my;    // msg(s->t) summed over sources s
            }
        }
    }
    // combine 16 s-chunk partials per t: butterfly over lanes {tl,+16,+32,+48}
    ax += __shfl_xor(ax, 16); ay += __shfl_xor(ay, 16);
    ax += __shfl_xor(ax, 32); ay += __shfl_xor(ay, 32);
    int wv = tid >> 6;
    if ((tid & 63) < 16) sred[wv][tl] = make_float2(ax, ay);
    __syncthreads();
    if (tid < 16){
        float2 r0 = sred[0][tid], r1 = sred[1][tid];
        float2 r2 = sred[2][tid], r3 = sred[3][tid];
        float2 basec = (LAYER == 1) ? c1s[t0 + tid] : c0s[t0 + tid];
        float2 o;
        o.x = basec.x + r0.x + r1.x + r2.x + r3.x;
        o.y = basec.y + r0.y + r1.y + r2.y + r3.y;
        ((float2*)outp)[(b << 11) + t0 + tid] = o;
    }
}

extern "C" void kernel_launch(void* const* d_in, const int* in_sizes, int n_in,
                              void* d_out, int out_size, void* d_ws, size_t ws_size,
                              hipStream_t stream){
    const float* coors     = (const float*)d_in[0];
    const float* globs_e   = (const float*)d_in[1];
    const float* W_e0      = (const float*)d_in[4];
    const float* W_r1      = (const float*)d_in[5];
    const float* W_r2      = (const float*)d_in[6];
    const float* W_g       = (const float*)d_in[7];
    const float* W_v1      = (const float*)d_in[8];
    const float* W_v2      = (const float*)d_in[9];
    const float* W_vo      = (const float*)d_in[10];
    const float* scale     = (const float*)d_in[11];
    const int*   src       = (const int*)d_in[12];
    const int*   tgt       = (const int*)d_in[13];

    int ne = in_sizes[12];

    char* w = (char*)d_ws;
    float* table  = (float*)w;                 // 8 KB
    float* coors1 = (float*)(w + 8192);        // 64 KB

    // 1) mij_hat(l, b, rd) lookup table: exact MLP at 256 samples per (l,b)
    k_table_sa<<<256, 256, 0, stream>>>(src, globs_e, ne, W_e0, W_r1, W_r2,
                                        W_g, W_v1, W_v2, W_vo, table);
    // 2) layer 0: coors1 = coors + update   (membership & rel from coors)
    k_nbody<0><<<512, 256, 0, stream>>>(coors, coors, table, scale,
                                        src, tgt, ne, coors1);
    // 3) layer 1: out = coors1 + update     (membership from coors, rel from coors1)
    k_nbody<1><<<512, 256, 0, stream>>>(coors, coors1, table, scale,
                                        src, tgt, ne, (float*)d_out);
}

// Round 12
// 169.469 us; speedup vs baseline: 1.3340x; 1.3340x over previous
//
#include <hip/hip_runtime.h>
#include <math.h>

#define CUTOFF    0.3927f
#define TWO_PI_F  6.283185307179586f
#define INV_2PI_F 0.15915494309189535f
#define INV_SQRT2 0.7071067811865476f
#define NB        4
#define NNODE     2048
#define HD        128
#define S_TAB     256
#define SG        8

__device__ __forceinline__ float sigmoidf_(float x){ return 1.0f/(1.0f+__expf(-x)); }
__device__ __forceinline__ float siluf_(float x){ return x*sigmoidf_(x); }
__device__ __forceinline__ float ssiluf_(float x){ return siluf_(x)*(1.0f/0.6f); }

// ---------------- table build: one block = (l, b, 8 samples) ----------------
struct TabSmem { float X[SG][HD+4]; float g[16]; int probe; };

__device__ __forceinline__ float4 gemv4(const float (*X)[HD+4], int sl,
                                        const float* __restrict__ W, int j0){
    float a0=0.f, a1=0.f, a2=0.f, a3=0.f;
    #pragma unroll 8
    for (int k=0;k<HD;k++){
        float x = X[sl][k];
        float4 w = *(const float4*)(W + k*HD + j0);
        a0 += x*w.x; a1 += x*w.y; a2 += x*w.z; a3 += x*w.w;
    }
    return make_float4(a0,a1,a2,a3);
}

__device__ void table_block(int blk, int tid,
                            const int* __restrict__ src, const float* __restrict__ globs_e,
                            int ne,
                            const float* __restrict__ W_e0, const float* __restrict__ W_r1,
                            const float* __restrict__ W_r2, const float* __restrict__ W_g,
                            const float* __restrict__ W_v1, const float* __restrict__ W_v2,
                            const float* __restrict__ W_vo, float* __restrict__ table,
                            TabSmem& sm){
    int sl = tid >> 5, jq = tid & 31, j0 = jq*4;
    int sg = blk & 31, b = (blk>>5)&3, l = blk>>7;

    // probe an edge of batch b to recover globs[b]
    if (tid == 0) sm.probe = 0x7fffffff;
    __syncthreads();
    int stride = ne >> 8; if (stride < 1) stride = 1;
    int e = tid*stride; if (e >= ne) e = ne-1;
    if ((src[e] >> 11) == b) atomicMin(&sm.probe, e);
    __syncthreads();
    int pe = sm.probe; if (pe == 0x7fffffff) pe = 0;
    if (tid < 16) sm.g[tid] = globs_e[(size_t)pe*16 + tid];
    __syncthreads();

    const float step = CUTOFF / (S_TAB - 1);
    float rd = (sg*SG + sl)*step;

    const float* We0 = W_e0 + l*17*HD;
    const float* Wr1 = W_r1 + l*HD*HD;
    const float* Wr2 = W_r2 + l*HD*HD;
    const float* Wg  = W_g  + l*HD;
    const float* Wv1 = W_v1 + l*HD*HD;
    const float* Wv2 = W_v2 + l*HD*HD;
    const float* Wvo = W_vo + l*HD;

    float4 p = make_float4(0,0,0,0);
    #pragma unroll
    for (int k=0;k<16;k++){
        float g = sm.g[k];
        float4 w = *(const float4*)(We0 + k*HD + j0);
        p.x += g*w.x; p.y += g*w.y; p.z += g*w.z; p.w += g*w.w;
    }
    float4 w16 = *(const float4*)(We0 + 16*HD + j0);
    float4 h;
    h.x = siluf_(ssiluf_(p.x + rd*w16.x));
    h.y = siluf_(ssiluf_(p.y + rd*w16.y));
    h.z = siluf_(ssiluf_(p.z + rd*w16.z));
    h.w = siluf_(ssiluf_(p.w + rd*w16.w));

    #define STORE4(v) { sm.X[sl][j0]=(v).x; sm.X[sl][j0+1]=(v).y; sm.X[sl][j0+2]=(v).z; sm.X[sl][j0+3]=(v).w; }
    #define SSILU4(v) make_float4(ssiluf_((v).x), ssiluf_((v).y), ssiluf_((v).z), ssiluf_((v).w))

    STORE4(h); __syncthreads();
    float4 t = gemv4(sm.X, sl, Wr1, j0); __syncthreads();
    t = SSILU4(t);
    STORE4(t); __syncthreads();
    float4 u = gemv4(sm.X, sl, Wr2, j0); __syncthreads();
    h.x = (h.x + ssiluf_(u.x))*INV_SQRT2;
    h.y = (h.y + ssiluf_(u.y))*INV_SQRT2;
    h.z = (h.z + ssiluf_(u.z))*INV_SQRT2;
    h.w = (h.w + ssiluf_(u.w))*INV_SQRT2;

    float4 wg = *(const float4*)(Wg + j0);
    float pg = h.x*wg.x + h.y*wg.y + h.z*wg.z + h.w*wg.w;
    #pragma unroll
    for (int off=16; off>0; off>>=1) pg += __shfl_xor(pg, off);
    float gt = sigmoidf_(pg);
    h.x*=gt; h.y*=gt; h.z*=gt; h.w*=gt;

    STORE4(h); __syncthreads();
    t = gemv4(sm.X, sl, Wv1, j0); __syncthreads();
    t = SSILU4(t);
    STORE4(t); __syncthreads();
    u = gemv4(sm.X, sl, Wv2, j0);
    float4 v;
    v.x = siluf_((h.x + ssiluf_(u.x))*INV_SQRT2);
    v.y = siluf_((h.y + ssiluf_(u.y))*INV_SQRT2);
    v.z = siluf_((h.z + ssiluf_(u.z))*INV_SQRT2);
    v.w = siluf_((h.w + ssiluf_(u.w))*INV_SQRT2);
    float4 wvo = *(const float4*)(Wvo + j0);
    float pv = v.x*wvo.x + v.y*wvo.y + v.z*wvo.z + v.w*wvo.w;
    #pragma unroll
    for (int off=16; off>0; off>>=1) pv += __shfl_xor(pv, off);
    if (jq == 0) table[(l*NB+b)*S_TAB + sg*SG + sl] = pv;
    #undef STORE4
    #undef SSILU4
}

__global__ __launch_bounds__(256)
void k_table_sa(const int* __restrict__ src, const float* __restrict__ globs_e,
                int ne,
                const float* __restrict__ W_e0, const float* __restrict__ W_r1,
                const float* __restrict__ W_r2, const float* __restrict__ W_g,
                const float* __restrict__ W_v1, const float* __restrict__ W_v2,
                const float* __restrict__ W_vo, float* __restrict__ table){
    __shared__ TabSmem tsm;
    table_block(blockIdx.x, threadIdx.x, src, globs_e, ne, W_e0, W_r1, W_r2,
                W_g, W_v1, W_v2, W_vo, table, tsm);
}

// ---------------- per-edge message ------------------------------------------
__device__ __forceinline__ bool edge_msg(const float* __restrict__ tab_b,
                                         float rx, float ry, float rd, float sc,
                                         float& mx, float& my){
    float d = rd * (1.0f/CUTOFF);
    if (d >= 1.0f) return false;
    float d2 = d*d;
    float d5 = d2*d2*d;
    float env = 1.0f + d5*(-21.0f + d*(35.0f + d*(-15.0f)));
    float u = rd * ((float)(S_TAB-1)/CUTOFF);
    int i1 = (int)u; if (i1 > S_TAB-1) i1 = S_TAB-1;
    float fr = u - (float)i1;
    int im = i1-1 < 0 ? 0 : i1-1;
    int i2 = i1+1 > S_TAB-1 ? S_TAB-1 : i1+1;
    int i3 = i1+2 > S_TAB-1 ? S_TAB-1 : i1+2;
    float p0=tab_b[im], p1=tab_b[i1], p2=tab_b[i2], p3=tab_b[i3];
    float mij = p1 + 0.5f*fr*((p2-p0) + fr*((2.f*p0-5.f*p1+4.f*p2-p3)
                               + fr*(3.f*(p1-p2)+p3-p0)));
    float nrm = sqrtf(rx*rx + ry*ry);
    float inv = 1.0f / fmaxf(nrm, 1e-8f);
    float wmul = mij * env * sc * inv;
    mx = wmul*rx; my = wmul*ry;
    return true;
}

// ---------------- N-body with per-wave compaction queue ---------------------
// Block = (batch, 8 targets). 256 threads = 8 t-lanes x 32 s-chunks of 64.
// Phase A per slot: bit-exact membership + rank(truncation) test only; valid
// (s,tl) entries are ballot-compacted into a per-wave queue. When the queue
// holds >=64 entries, one dense drain iteration runs edge_msg with ALL lanes
// active (vs ~2/64 under naive divergence). Accumulate per-wave in LDS.
template<int LAYER>
__global__ __launch_bounds__(256)
void k_nbody(const float* __restrict__ coors0, const float* __restrict__ ccur,
             const float* __restrict__ table_g, const float* __restrict__ scale,
             const int* __restrict__ src, const int* __restrict__ tgt,
             int ne, float* __restrict__ outp){
    __shared__ float2 cs0[NNODE];                 // 16 KB original coords
    __shared__ float2 cs1[LAYER ? NNODE : 1];     // 16 KB layer-1 coords
    __shared__ float  tabs[S_TAB];                // 1 KB
    __shared__ float2 tc0[8], tc1[8];
    __shared__ ushort qarr[4][128];               // per-wave queue
    __shared__ float2 acc[4][8];                  // per-wave per-target sums

    int tid = threadIdx.x, blk = blockIdx.x;
    int b  = blk >> 8;                  // 4 batches x 256 blocks
    int t0 = (blk & 255) * 8;
    int tl = tid & 7;                   // target lane
    int sk = tid >> 3;                  // 32 source chunks of 64
    int wv = tid >> 6, lane = tid & 63;

    const float2* cb0 = ((const float2*)coors0) + (b << 11);
    const float2* cb1 = ((const float2*)ccur)  + (b << 11);
    for (int i = tid; i < NNODE; i += 256) cs0[i] = cb0[i];
    if (LAYER == 1) for (int i = tid; i < NNODE; i += 256) cs1[i] = cb1[i];
    for (int i = tid; i < S_TAB; i += 256)
        tabs[i] = table_g[LAYER*NB*S_TAB + b*S_TAB + i];
    if (tid < 8){
        tc0[tid] = cb0[t0 + tid];
        if (LAYER == 1) tc1[tid] = cb1[t0 + tid];
    }
    if (tid < 32) acc[tid>>3][tid&7] = make_float2(0.f, 0.f);

    int ic  = src[ne-1];                // truncation frontier
    int jcg = tgt[ne-1];
    bool keep_all = (ic == 0 && jcg == 0);
    float sc = scale[LAYER];
    __syncthreads();

    float2 ci0 = tc0[tl];
    int tg = (b << 11) + t0 + tl;
    int base = sk * 64;
    unsigned long long lmask = (1ull << lane) - 1ull;
    int qn = 0;

    #define PROCESS(eidx) {                                                  \
        int ps = (eidx) & 2047; int ptl = (eidx) >> 11;                      \
        float rx, ry, rd;                                                    \
        if (LAYER == 0){                                                     \
            float2 ti = tc0[ptl]; float2 cj = cs0[ps];                       \
            rx = ti.x - cj.x; ry = ti.y - cj.y;                              \
            rx -= TWO_PI_F * rintf(rx * INV_2PI_F);                          \
            ry -= TWO_PI_F * rintf(ry * INV_2PI_F);                          \
            rd = rx*rx + ry*ry;                                              \
        } else {                                                             \
            float2 ti = tc1[ptl]; float2 cj = cs1[ps];                       \
            rx = ti.x - cj.x; ry = ti.y - cj.y;                              \
            rx -= TWO_PI_F * rintf(rx * INV_2PI_F);                          \
            ry -= TWO_PI_F * rintf(ry * INV_2PI_F);                          \
            rd = rx*rx + ry*ry;                                              \
        }                                                                    \
        float mx, my;                                                        \
        if (edge_msg(tabs, rx, ry, rd, sc, mx, my)){                         \
            atomicAdd(&acc[wv][ptl].x, mx);                                  \
            atomicAdd(&acc[wv][ptl].y, my);                                  \
        }                                                                    \
    }

    for (int ii = 0; ii < 64; ii++){
        int s = base + ii;
        float2 cj = cs0[s];
        // membership: bit-exact setup replica (f32, no fma)
        float dx = __fsub_rn(ci0.x, cj.x);
        float dy = __fsub_rn(ci0.y, cj.y);
        float kx = rintf(dx * INV_2PI_F);
        float ky = rintf(dy * INV_2PI_F);
        float wx = __fsub_rn(dx, __fmul_rn(TWO_PI_F, kx));
        float wy = __fsub_rn(dy, __fmul_rn(TWO_PI_F, ky));
        float d2 = __fadd_rn(__fmul_rn(wx,wx), __fmul_rn(wy,wy));
        bool valid = (d2 > 0.0f) && (d2 <= CUTOFF);
        if (valid && !keep_all){
            int sg_ = (b << 11) + s;    // kept iff row-major rank <= frontier
            valid = (sg_ < ic) || (sg_ == ic && tg <= jcg);
        }
        unsigned long long mask = __ballot(valid);
        if (valid){
            int off = __popcll(mask & lmask);
            qarr[wv][qn + off] = (ushort)(s | (tl << 11));
        }
        qn += (int)__popcll(mask);
        if (qn >= 64){                  // dense drain: all 64 lanes active
            qn -= 64;
            ushort e = qarr[wv][qn + lane];
            PROCESS(e);
        }
    }
    if (lane < qn){                     // remainder drain
        ushort e = qarr[wv][lane];
        PROCESS(e);
    }
    #undef PROCESS

    __syncthreads();
    if (tid < 8){
        float2 a0 = acc[0][tid], a1 = acc[1][tid];
        float2 a2 = acc[2][tid], a3 = acc[3][tid];
        float2 basec = (LAYER == 1) ? tc1[tid] : tc0[tid];
        float2 o;
        o.x = basec.x + a0.x + a1.x + a2.x + a3.x;
        o.y = basec.y + a0.y + a1.y + a2.y + a3.y;
        ((float2*)outp)[(b << 11) + t0 + tid] = o;
    }
}

extern "C" void kernel_launch(void* const* d_in, const int* in_sizes, int n_in,
                              void* d_out, int out_size, void* d_ws, size_t ws_size,
                              hipStream_t stream){
    const float* coors     = (const float*)d_in[0];
    const float* globs_e   = (const float*)d_in[1];
    const float* W_e0      = (const float*)d_in[4];
    const float* W_r1      = (const float*)d_in[5];
    const float* W_r2      = (const float*)d_in[6];
    const float* W_g       = (const float*)d_in[7];
    const float* W_v1      = (const float*)d_in[8];
    const float* W_v2      = (const float*)d_in[9];
    const float* W_vo      = (const float*)d_in[10];
    const float* scale     = (const float*)d_in[11];
    const int*   src       = (const int*)d_in[12];
    const int*   tgt       = (const int*)d_in[13];

    int ne = in_sizes[12];

    char* w = (char*)d_ws;
    float* table  = (float*)w;                 // 8 KB
    float* coors1 = (float*)(w + 8192);        // 64 KB

    // 1) mij_hat(l, b, rd) lookup table: exact MLP at 256 samples per (l,b)
    k_table_sa<<<256, 256, 0, stream>>>(src, globs_e, ne, W_e0, W_r1, W_r2,
                                        W_g, W_v1, W_v2, W_vo, table);
    // 2) layer 0: coors1 = coors + update
    k_nbody<0><<<1024, 256, 0, stream>>>(coors, coors, table, scale,
                                         src, tgt, ne, coors1);
    // 3) layer 1: out = coors1 + update (membership from coors, rel from coors1)
    k_nbody<1><<<1024, 256, 0, stream>>>(coors, coors1, table, scale,
                                         src, tgt, ne, (float*)d_out);
}

// Round 15
// 157.573 us; speedup vs baseline: 1.4348x; 1.0755x over previous
//
#include <hip/hip_runtime.h>
#include <math.h>

#define CUTOFF    0.3927f
#define TWO_PI_F  6.283185307179586f
#define INV_2PI_F 0.15915494309189535f
#define INV_SQRT2 0.7071067811865476f
#define NB        4
#define NNODE     2048
#define HD        128
#define S_TAB     256
#define SG        8

__device__ __forceinline__ float sigmoidf_(float x){ return 1.0f/(1.0f+__expf(-x)); }
__device__ __forceinline__ float siluf_(float x){ return x*sigmoidf_(x); }
__device__ __forceinline__ float ssiluf_(float x){ return siluf_(x)*(1.0f/0.6f); }

// ---------------- table build: one block = (l, b, 8 samples) ----------------
struct TabSmem { float X[SG][HD+4]; float g[16]; int probe; };

__device__ __forceinline__ float4 gemv4(const float (*X)[HD+4], int sl,
                                        const float* __restrict__ W, int j0){
    float a0=0.f, a1=0.f, a2=0.f, a3=0.f;
    #pragma unroll 8
    for (int k=0;k<HD;k++){
        float x = X[sl][k];
        float4 w = *(const float4*)(W + k*HD + j0);
        a0 += x*w.x; a1 += x*w.y; a2 += x*w.z; a3 += x*w.w;
    }
    return make_float4(a0,a1,a2,a3);
}

__device__ void table_block(int blk, int tid,
                            const int* __restrict__ src, const float* __restrict__ globs_e,
                            int ne,
                            const float* __restrict__ W_e0, const float* __restrict__ W_r1,
                            const float* __restrict__ W_r2, const float* __restrict__ W_g,
                            const float* __restrict__ W_v1, const float* __restrict__ W_v2,
                            const float* __restrict__ W_vo, float* __restrict__ table,
                            TabSmem& sm){
    int sl = tid >> 5, jq = tid & 31, j0 = jq*4;
    int sg = blk & 31, b = (blk>>5)&3, l = blk>>7;

    // probe an edge of batch b to recover globs[b]
    if (tid == 0) sm.probe = 0x7fffffff;
    __syncthreads();
    int stride = ne >> 8; if (stride < 1) stride = 1;
    int e = tid*stride; if (e >= ne) e = ne-1;
    if ((src[e] >> 11) == b) atomicMin(&sm.probe, e);
    __syncthreads();
    int pe = sm.probe; if (pe == 0x7fffffff) pe = 0;
    if (tid < 16) sm.g[tid] = globs_e[(size_t)pe*16 + tid];
    __syncthreads();

    const float step = CUTOFF / (S_TAB - 1);
    float rd = (sg*SG + sl)*step;

    const float* We0 = W_e0 + l*17*HD;
    const float* Wr1 = W_r1 + l*HD*HD;
    const float* Wr2 = W_r2 + l*HD*HD;
    const float* Wg  = W_g  + l*HD;
    const float* Wv1 = W_v1 + l*HD*HD;
    const float* Wv2 = W_v2 + l*HD*HD;
    const float* Wvo = W_vo + l*HD;

    float4 p = make_float4(0,0,0,0);
    #pragma unroll
    for (int k=0;k<16;k++){
        float g = sm.g[k];
        float4 w = *(const float4*)(We0 + k*HD + j0);
        p.x += g*w.x; p.y += g*w.y; p.z += g*w.z; p.w += g*w.w;
    }
    float4 w16 = *(const float4*)(We0 + 16*HD + j0);
    float4 h;
    h.x = siluf_(ssiluf_(p.x + rd*w16.x));
    h.y = siluf_(ssiluf_(p.y + rd*w16.y));
    h.z = siluf_(ssiluf_(p.z + rd*w16.z));
    h.w = siluf_(ssiluf_(p.w + rd*w16.w));

    #define STORE4(v) { sm.X[sl][j0]=(v).x; sm.X[sl][j0+1]=(v).y; sm.X[sl][j0+2]=(v).z; sm.X[sl][j0+3]=(v).w; }
    #define SSILU4(v) make_float4(ssiluf_((v).x), ssiluf_((v).y), ssiluf_((v).z), ssiluf_((v).w))

    STORE4(h); __syncthreads();
    float4 t = gemv4(sm.X, sl, Wr1, j0); __syncthreads();
    t = SSILU4(t);
    STORE4(t); __syncthreads();
    float4 u = gemv4(sm.X, sl, Wr2, j0); __syncthreads();
    h.x = (h.x + ssiluf_(u.x))*INV_SQRT2;
    h.y = (h.y + ssiluf_(u.y))*INV_SQRT2;
    h.z = (h.z + ssiluf_(u.z))*INV_SQRT2;
    h.w = (h.w + ssiluf_(u.w))*INV_SQRT2;

    float4 wg = *(const float4*)(Wg + j0);
    float pg = h.x*wg.x + h.y*wg.y + h.z*wg.z + h.w*wg.w;
    #pragma unroll
    for (int off=16; off>0; off>>=1) pg += __shfl_xor(pg, off);
    float gt = sigmoidf_(pg);
    h.x*=gt; h.y*=gt; h.z*=gt; h.w*=gt;

    STORE4(h); __syncthreads();
    t = gemv4(sm.X, sl, Wv1, j0); __syncthreads();
    t = SSILU4(t);
    STORE4(t); __syncthreads();
    u = gemv4(sm.X, sl, Wv2, j0);
    float4 v;
    v.x = siluf_((h.x + ssiluf_(u.x))*INV_SQRT2);
    v.y = siluf_((h.y + ssiluf_(u.y))*INV_SQRT2);
    v.z = siluf_((h.z + ssiluf_(u.z))*INV_SQRT2);
    v.w = siluf_((h.w + ssiluf_(u.w))*INV_SQRT2);
    float4 wvo = *(const float4*)(Wvo + j0);
    float pv = v.x*wvo.x + v.y*wvo.y + v.z*wvo.z + v.w*wvo.w;
    #pragma unroll
    for (int off=16; off>0; off>>=1) pv += __shfl_xor(pv, off);
    if (jq == 0) table[(l*NB+b)*S_TAB + sg*SG + sl] = pv;
    #undef STORE4
    #undef SSILU4
}

__global__ __launch_bounds__(256)
void k_table_sa(const int* __restrict__ src, const float* __restrict__ globs_e,
                int ne,
                const float* __restrict__ W_e0, const float* __restrict__ W_r1,
                const float* __restrict__ W_r2, const float* __restrict__ W_g,
                const float* __restrict__ W_v1, const float* __restrict__ W_v2,
                const float* __restrict__ W_vo, float* __restrict__ table){
    __shared__ TabSmem tsm;
    table_block(blockIdx.x, threadIdx.x, src, globs_e, ne, W_e0, W_r1, W_r2,
                W_g, W_v1, W_v2, W_vo, table, tsm);
}

// ---------------- per-edge message ------------------------------------------
__device__ __forceinline__ bool edge_msg(const float* __restrict__ tab_b,
                                         float rx, float ry, float rd, float sc,
                                         float& mx, float& my){
    float d = rd * (1.0f/CUTOFF);
    if (d >= 1.0f) return false;
    float d2 = d*d;
    float d5 = d2*d2*d;
    float env = 1.0f + d5*(-21.0f + d*(35.0f + d*(-15.0f)));
    float u = rd * ((float)(S_TAB-1)/CUTOFF);
    int i1 = (int)u; if (i1 > S_TAB-1) i1 = S_TAB-1;
    float fr = u - (float)i1;
    int im = i1-1 < 0 ? 0 : i1-1;
    int i2 = i1+1 > S_TAB-1 ? S_TAB-1 : i1+1;
    int i3 = i1+2 > S_TAB-1 ? S_TAB-1 : i1+2;
    float p0=tab_b[im], p1=tab_b[i1], p2=tab_b[i2], p3=tab_b[i3];
    float mij = p1 + 0.5f*fr*((p2-p0) + fr*((2.f*p0-5.f*p1+4.f*p2-p3)
                               + fr*(3.f*(p1-p2)+p3-p0)));
    float nrm = sqrtf(rx*rx + ry*ry);
    float inv = 1.0f / fmaxf(nrm, 1e-8f);
    float wmul = mij * env * sc * inv;
    mx = wmul*rx; my = wmul*ry;
    return true;
}

// ---------------- N-body with per-wave compaction queue, 8 blocks/CU --------
// Block = (batch, 4 targets). 256 threads = 4 t-lanes x 64 s-chunks of 32.
// Membership (bit-exact replica, original coords from LDS) ballot-compacts
// valid (s,tl) into a per-wave queue; drains run edge_msg fully dense.
// Layer-1 source coords are read from L2 in the (cold) drain path, so LDS
// stays ~18 KB -> 8 blocks/CU (vs 34 KB/4 blocks before).
template<int LAYER>
__global__ __launch_bounds__(256, 8)
void k_nbody(const float* __restrict__ coors0, const float* __restrict__ ccur,
             const float* __restrict__ table_g, const float* __restrict__ scale,
             const int* __restrict__ src, const int* __restrict__ tgt,
             int ne, float* __restrict__ outp){
    __shared__ float2 cs0[NNODE];                 // 16 KB original coords
    __shared__ float  tabs[S_TAB];                // 1 KB
    __shared__ float2 tor0[4], tcur[4];
    __shared__ ushort qarr[4][128];               // per-wave queue
    __shared__ float2 acc[4][4];                  // per-wave per-target sums

    int tid = threadIdx.x, blk = blockIdx.x;
    int b  = blk >> 9;                  // 4 batches x 512 blocks
    int t0 = (blk & 511) * 4;
    int tl = tid & 3;                   // target lane
    int sk = tid >> 2;                  // 64 source chunks of 32
    int wv = tid >> 6, lane = tid & 63;

    const float2* cb0 = ((const float2*)coors0) + (b << 11);
    const float2* cb1 = ((const float2*)ccur)  + (b << 11);
    {   // vectorized cs0 fill (float4 = 2 nodes)
        const float4* g4 = (const float4*)cb0;
        float4* s4 = (float4*)cs0;
        for (int i = tid; i < NNODE/2; i += 256) s4[i] = g4[i];
    }
    for (int i = tid; i < S_TAB; i += 256)
        tabs[i] = table_g[LAYER*NB*S_TAB + b*S_TAB + i];
    if (tid < 4){
        tor0[tid] = cb0[t0 + tid];
        tcur[tid] = LAYER ? cb1[t0 + tid] : cb0[t0 + tid];
    }
    if (tid < 16) acc[tid>>2][tid&3] = make_float2(0.f, 0.f);

    int ic  = src[ne-1];                // truncation frontier
    int jcg = tgt[ne-1];
    bool keep_all = (ic == 0 && jcg == 0);
    float sc = scale[LAYER];
    __syncthreads();

    float2 ci0 = tor0[tl];
    int tg = (b << 11) + t0 + tl;
    int base = sk * 32;
    unsigned long long lmask = (1ull << lane) - 1ull;
    int qn = 0;

    #define PROCESS(eidx) {                                                  \
        int ps = (eidx) & 2047; int ptl = (eidx) >> 11;                      \
        float2 ti = tcur[ptl];                                               \
        float2 cj = LAYER ? cb1[ps] : cs0[ps];                               \
        float rx = ti.x - cj.x, ry = ti.y - cj.y;                            \
        rx -= TWO_PI_F * rintf(rx * INV_2PI_F);                              \
        ry -= TWO_PI_F * rintf(ry * INV_2PI_F);                              \
        float rd = rx*rx + ry*ry;                                            \
        float mx, my;                                                        \
        if (edge_msg(tabs, rx, ry, rd, sc, mx, my)){                         \
            atomicAdd(&acc[wv][ptl].x, mx);                                  \
            atomicAdd(&acc[wv][ptl].y, my);                                  \
        }                                                                    \
    }

    #define MEMBER_STEP(s_, cjx_, cjy_) {                                    \
        float dx = __fsub_rn(ci0.x, (cjx_));                                 \
        float dy = __fsub_rn(ci0.y, (cjy_));                                 \
        float kx = rintf(dx * INV_2PI_F);                                    \
        float ky = rintf(dy * INV_2PI_F);                                    \
        float wx = __fsub_rn(dx, __fmul_rn(TWO_PI_F, kx));                   \
        float wy = __fsub_rn(dy, __fmul_rn(TWO_PI_F, ky));                   \
        float d2 = __fadd_rn(__fmul_rn(wx,wx), __fmul_rn(wy,wy));            \
        bool valid = (d2 > 0.0f) && (d2 <= CUTOFF);                          \
        if (valid && !keep_all){                                             \
            int sg_ = (b << 11) + (s_);                                      \
            valid = (sg_ < ic) || (sg_ == ic && tg <= jcg);                  \
        }                                                                    \
        unsigned long long mask = __ballot(valid);                           \
        if (valid){                                                          \
            int off = __popcll(mask & lmask);                                \
            qarr[wv][qn + off] = (ushort)((s_) | (tl << 11));                \
        }                                                                    \
        qn += (int)__popcll(mask);                                           \
        if (qn >= 64){                                                       \
            qn -= 64;                                                        \
            ushort e = qarr[wv][qn + lane];                                  \
            PROCESS(e);                                                      \
        }                                                                    \
    }

    for (int ii = 0; ii < 16; ii++){
        int s = base + ii*2;
        float4 v2 = *(const float4*)&cs0[s];     // 2 nodes per LDS read
        MEMBER_STEP(s,     v2.x, v2.y);
        MEMBER_STEP(s + 1, v2.z, v2.w);
    }
    if (lane < qn){                     // remainder drain
        ushort e = qarr[wv][lane];
        PROCESS(e);
    }
    #undef MEMBER_STEP
    #undef PROCESS

    __syncthreads();
    if (tid < 4){
        float2 a0 = acc[0][tid], a1 = acc[1][tid];
        float2 a2 = acc[2][tid], a3 = acc[3][tid];
        float2 basec = tcur[tid];
        float2 o;
        o.x = basec.x + a0.x + a1.x + a2.x + a3.x;
        o.y = basec.y + a0.y + a1.y + a2.y + a3.y;
        ((float2*)outp)[(b << 11) + t0 + tid] = o;
    }
}

extern "C" void kernel_launch(void* const* d_in, const int* in_sizes, int n_in,
                              void* d_out, int out_size, void* d_ws, size_t ws_size,
                              hipStream_t stream){
    const float* coors     = (const float*)d_in[0];
    const float* globs_e   = (const float*)d_in[1];
    const float* W_e0      = (const float*)d_in[4];
    const float* W_r1      = (const float*)d_in[5];
    const float* W_r2      = (const float*)d_in[6];
    const float* W_g       = (const float*)d_in[7];
    const float* W_v1      = (const float*)d_in[8];
    const float* W_v2      = (const float*)d_in[9];
    const float* W_vo      = (const float*)d_in[10];
    const float* scale     = (const float*)d_in[11];
    const int*   src       = (const int*)d_in[12];
    const int*   tgt       = (const int*)d_in[13];

    int ne = in_sizes[12];

    char* w = (char*)d_ws;
    float* table  = (float*)w;                 // 8 KB
    float* coors1 = (float*)(w + 8192);        // 64 KB

    // 1) mij_hat(l, b, rd) lookup table: exact MLP at 256 samples per (l,b)
    k_table_sa<<<256, 256, 0, stream>>>(src, globs_e, ne, W_e0, W_r1, W_r2,
                                        W_g, W_v1, W_v2, W_vo, table);
    // 2) layer 0: coors1 = coors + update
    k_nbody<0><<<2048, 256, 0, stream>>>(coors, coors, table, scale,
                                         src, tgt, ne, coors1);
    // 3) layer 1: out = coors1 + update (membership from coors, rel from coors1)
    k_nbody<1><<<2048, 256, 0, stream>>>(coors, coors1, table, scale,
                                         src, tgt, ne, (float*)d_out);
}